// Round 11
// baseline (313.276 us; speedup 1.0000x reference)
//
#include <hip/hip_runtime.h>
#include <math.h>

#define LEVELS 16
#define FEAT 2

// Ns[l] = python round(16 * 1.5^l)  (banker's rounding; exact in fp32)
__constant__ float c_Ns[LEVELS] = {
    16.f, 24.f, 36.f, 54.f, 81.f, 122.f, 182.f, 273.f,
    410.f, 615.f, 923.f, 1384.f, 2076.f, 3114.f, 4671.f, 7006.f
};

#define P1 2654435761u
#define P2 805459861u

template <bool POW2_TABLE>
__device__ __forceinline__ unsigned hash2d(unsigned ux, unsigned uy, unsigned sd,
                                           unsigned tsize, unsigned tmask) {
    const unsigned h = (ux * P1) ^ (uy * P2) ^ sd;
    return POW2_TABLE ? (h & tmask) : (h % tsize);
}

// FINE_MEM=true : levels 12..15 gather from the table (correct kernel).
// FINE_MEM=false: levels 12..15 synthesize f-values from the hash indices
//                 (keeps ALL hash/index VALU live, removes only the 16 random
//                 memory loads) — the ablation probe. Its output is garbage in
//                 the fine channels; the correct kernel runs after and
//                 overwrites every element of d_out.
template <bool POW2_TABLE, bool POW2_W, bool FINE_MEM>
__global__ __launch_bounds__(256) void hashenc_kernel(
    const float* __restrict__ x0,
    const float* __restrict__ y0,
    const float2* __restrict__ tables,
    const unsigned int* __restrict__ seeds,
    const int* __restrict__ tile_ptr,
    float* __restrict__ out,
    int N, int W, int wshift,
    unsigned int tsize, unsigned int tmask)
{
    const int pix = blockIdx.x * blockDim.x + threadIdx.x;
    if (pix >= N) return;
    const int b = blockIdx.y;

    int i, j;
    if (POW2_W) { i = pix >> wshift; j = pix & (W - 1); }
    else        { i = pix / W;       j = pix - i * W;   }

    // scales: bit-exact vs reference f32 Ns/tile (pow2 tile -> exact rcp)
    const int tile = *tile_ptr;
    const float tilef = (float)tile;
    float sc[LEVELS];
    if ((tile & (tile - 1)) == 0) {
        const float it = 1.0f / tilef;
#pragma unroll
        for (int l = 0; l < LEVELS; ++l) sc[l] = c_Ns[l] * it;
    } else {
#pragma unroll
        for (int l = 0; l < LEVELS; ++l) sc[l] = c_Ns[l] / tilef;
    }

    const float px = (float)j + x0[b];
    const float py = (float)i + y0[b];
    float* outb = out + (size_t)b * (size_t)(LEVELS * FEAT) * (size_t)N + pix;

#pragma unroll
    for (int l = 0; l < LEVELS; ++l) {
        const float s = sc[l];
        const float xs = px * s, ys = py * s;
        const float fx0 = floorf(xs), fy0 = floorf(ys);
        const float fx = xs - fx0, fy = ys - fy0;
        const unsigned ux = (unsigned)(int)fx0;
        const unsigned uy = (unsigned)(int)fy0;
        const unsigned sd = seeds[l];
        const unsigned i00 = hash2d<POW2_TABLE>(ux,      uy,      sd, tsize, tmask);
        const unsigned i10 = hash2d<POW2_TABLE>(ux + 1u, uy,      sd, tsize, tmask);
        const unsigned i01 = hash2d<POW2_TABLE>(ux,      uy + 1u, sd, tsize, tmask);
        const unsigned i11 = hash2d<POW2_TABLE>(ux + 1u, uy + 1u, sd, tsize, tmask);

        float2 f00, f10, f01, f11;
        if (FINE_MEM || l < 12) {
            f00 = tables[i00];
            f10 = tables[i10];
            f01 = tables[i01];
            f11 = tables[i11];
        } else {
            // ablation: hash indices stay live (VALU identical), loads removed
            f00 = make_float2((float)(int)i00 * 0x1p-30f, (float)(int)i10 * 0x1p-30f);
            f10 = make_float2((float)(int)i10 * 0x1p-30f, (float)(int)i01 * 0x1p-30f);
            f01 = make_float2((float)(int)i01 * 0x1p-30f, (float)(int)i11 * 0x1p-30f);
            f11 = make_float2((float)(int)i11 * 0x1p-30f, (float)(int)i00 * 0x1p-30f);
        }

        const float omx = 1.0f - fx, omy = 1.0f - fy;
        const float w00 = omx * omy, w10 = fx * omy;
        const float w01 = omx * fy, w11 = fx * fy;
        const float e0 = w00 * f00.x + w10 * f10.x + w01 * f01.x + w11 * f11.x;
        const float e1 = w00 * f00.y + w10 * f10.y + w01 * f01.y + w11 * f11.y;

        __builtin_nontemporal_store(e0, outb + (size_t)(2 * l) * (size_t)N);
        __builtin_nontemporal_store(e1, outb + (size_t)(2 * l + 1) * (size_t)N);
    }
}

extern "C" void kernel_launch(void* const* d_in, const int* in_sizes, int n_in,
                              void* d_out, int out_size, void* d_ws, size_t ws_size,
                              hipStream_t stream) {
    const float* x0 = (const float*)d_in[0];
    const float* y0 = (const float*)d_in[1];
    const float2* tables = (const float2*)d_in[2];
    const unsigned int* seeds = (const unsigned int*)d_in[3];
    // d_in[4] = memorized_crop_size (geometry derived from out_size)
    const int* tile_ptr = (const int*)d_in[5];

    const int Bn = in_sizes[0];
    const unsigned int tsize = (unsigned int)(in_sizes[2] / FEAT);
    const int N = out_size / (Bn * LEVELS * FEAT);       // H*W
    const int W = (int)(sqrt((double)N) + 0.5);          // H == W in reference
    int wshift = 0;
    while ((1 << wshift) < W) ++wshift;
    float* out = (float*)d_out;

    dim3 grid((N + 255) / 256, Bn);
    const bool pow2_table = (tsize & (tsize - 1)) == 0;
    const bool pow2_w = (W & (W - 1)) == 0;

    // --- ablation probe first (garbage in fine channels) ---
    if (pow2_table && pow2_w)
        hashenc_kernel<true, true, false><<<grid, 256, 0, stream>>>(
            x0, y0, tables, seeds, tile_ptr, out, N, W, wshift, tsize, tsize - 1u);
    else if (pow2_table)
        hashenc_kernel<true, false, false><<<grid, 256, 0, stream>>>(
            x0, y0, tables, seeds, tile_ptr, out, N, W, wshift, tsize, tsize - 1u);
    else if (pow2_w)
        hashenc_kernel<false, true, false><<<grid, 256, 0, stream>>>(
            x0, y0, tables, seeds, tile_ptr, out, N, W, wshift, tsize, 0u);
    else
        hashenc_kernel<false, false, false><<<grid, 256, 0, stream>>>(
            x0, y0, tables, seeds, tile_ptr, out, N, W, wshift, tsize, 0u);

    // --- correct kernel last: overwrites every element of d_out ---
    if (pow2_table && pow2_w)
        hashenc_kernel<true, true, true><<<grid, 256, 0, stream>>>(
            x0, y0, tables, seeds, tile_ptr, out, N, W, wshift, tsize, tsize - 1u);
    else if (pow2_table)
        hashenc_kernel<true, false, true><<<grid, 256, 0, stream>>>(
            x0, y0, tables, seeds, tile_ptr, out, N, W, wshift, tsize, tsize - 1u);
    else if (pow2_w)
        hashenc_kernel<false, true, true><<<grid, 256, 0, stream>>>(
            x0, y0, tables, seeds, tile_ptr, out, N, W, wshift, tsize, 0u);
    else
        hashenc_kernel<false, false, true><<<grid, 256, 0, stream>>>(
            x0, y0, tables, seeds, tile_ptr, out, N, W, wshift, tsize, 0u);
}

// Round 13
// 255.077 us; speedup vs baseline: 1.2282x; 1.2282x over previous
//
#include <hip/hip_runtime.h>
#include <math.h>

#define LEVELS 16
#define FEAT 2
#define NFINE 12   // levels >= NFINE use non-temporal (L1-bypass) loads

// Ns[l] = python round(16 * 1.5^l)  (banker's rounding; exact in fp32)
__constant__ float c_Ns[LEVELS] = {
    16.f, 24.f, 36.f, 54.f, 81.f, 122.f, 182.f, 273.f,
    410.f, 615.f, 923.f, 1384.f, 2076.f, 3114.f, 4671.f, 7006.f
};

#define P1 2654435761u
#define P2 805459861u

// clang vector type: __builtin_nontemporal_load accepts this (not HIP float2)
typedef float vfloat2 __attribute__((ext_vector_type(2)));

template <bool POW2_TABLE>
__device__ __forceinline__ unsigned hash2d(unsigned ux, unsigned uy, unsigned sd,
                                           unsigned tsize, unsigned tmask) {
    const unsigned h = (ux * P1) ^ (uy * P2) ^ sd;
    return POW2_TABLE ? (h & tmask) : (h % tsize);
}

template <bool POW2_TABLE, bool POW2_W>
__global__ __launch_bounds__(256) void hashenc_kernel(
    const float* __restrict__ x0,
    const float* __restrict__ y0,
    const vfloat2* __restrict__ tables,
    const unsigned int* __restrict__ seeds,
    const int* __restrict__ tile_ptr,
    float* __restrict__ out,
    int N, int W, int wshift,
    unsigned int tsize, unsigned int tmask)
{
    const int pix = blockIdx.x * blockDim.x + threadIdx.x;
    if (pix >= N) return;
    const int b = blockIdx.y;

    int i, j;
    if (POW2_W) { i = pix >> wshift; j = pix & (W - 1); }
    else        { i = pix / W;       j = pix - i * W;   }

    // scales: bit-exact vs reference f32 Ns/tile (pow2 tile -> exact rcp)
    const int tile = *tile_ptr;
    const float tilef = (float)tile;
    float sc[LEVELS];
    if ((tile & (tile - 1)) == 0) {
        const float it = 1.0f / tilef;
#pragma unroll
        for (int l = 0; l < LEVELS; ++l) sc[l] = c_Ns[l] * it;
    } else {
#pragma unroll
        for (int l = 0; l < LEVELS; ++l) sc[l] = c_Ns[l] / tilef;
    }

    const float px = (float)j + x0[b];
    const float py = (float)i + y0[b];
    float* outb = out + (size_t)b * (size_t)(LEVELS * FEAT) * (size_t)N + pix;

#pragma unroll
    for (int l = 0; l < LEVELS; ++l) {
        const float s = sc[l];
        const float xs = px * s, ys = py * s;
        const float fx0 = floorf(xs), fy0 = floorf(ys);
        const float fx = xs - fx0, fy = ys - fy0;
        const unsigned ux = (unsigned)(int)fx0;
        const unsigned uy = (unsigned)(int)fy0;
        const unsigned sd = seeds[l];
        const unsigned i00 = hash2d<POW2_TABLE>(ux,      uy,      sd, tsize, tmask);
        const unsigned i10 = hash2d<POW2_TABLE>(ux + 1u, uy,      sd, tsize, tmask);
        const unsigned i01 = hash2d<POW2_TABLE>(ux,      uy + 1u, sd, tsize, tmask);
        const unsigned i11 = hash2d<POW2_TABLE>(ux + 1u, uy + 1u, sd, tsize, tmask);

        vfloat2 f00, f10, f01, f11;
        if (l < NFINE) {
            // coarse: small per-CU working set -> let L1 cache it
            f00 = tables[i00];
            f10 = tables[i10];
            f01 = tables[i01];
            f11 = tables[i11];
        } else {
            // fine: hash-random over 4 MiB, ~100% L1 miss. Non-temporal ->
            // no L1 allocation: keeps coarse lines resident (kills the
            // eviction interaction) and skips alloc work on the miss path.
            f00 = __builtin_nontemporal_load(tables + i00);
            f10 = __builtin_nontemporal_load(tables + i10);
            f01 = __builtin_nontemporal_load(tables + i01);
            f11 = __builtin_nontemporal_load(tables + i11);
        }

        const float omx = 1.0f - fx, omy = 1.0f - fy;
        const float w00 = omx * omy, w10 = fx * omy;
        const float w01 = omx * fy, w11 = fx * fy;
        const float e0 = w00 * f00.x + w10 * f10.x + w01 * f01.x + w11 * f11.x;
        const float e1 = w00 * f00.y + w10 * f10.y + w01 * f01.y + w11 * f11.y;

        // nt stores: don't let 128 MiB of streaming stores thrash L2
        __builtin_nontemporal_store(e0, outb + (size_t)(2 * l) * (size_t)N);
        __builtin_nontemporal_store(e1, outb + (size_t)(2 * l + 1) * (size_t)N);
    }
}

extern "C" void kernel_launch(void* const* d_in, const int* in_sizes, int n_in,
                              void* d_out, int out_size, void* d_ws, size_t ws_size,
                              hipStream_t stream) {
    const float* x0 = (const float*)d_in[0];
    const float* y0 = (const float*)d_in[1];
    const vfloat2* tables = (const vfloat2*)d_in[2];
    const unsigned int* seeds = (const unsigned int*)d_in[3];
    // d_in[4] = memorized_crop_size (geometry derived from out_size)
    const int* tile_ptr = (const int*)d_in[5];

    const int Bn = in_sizes[0];
    const unsigned int tsize = (unsigned int)(in_sizes[2] / FEAT);
    const int N = out_size / (Bn * LEVELS * FEAT);       // H*W
    const int W = (int)(sqrt((double)N) + 0.5);          // H == W in reference
    int wshift = 0;
    while ((1 << wshift) < W) ++wshift;
    float* out = (float*)d_out;

    dim3 grid((N + 255) / 256, Bn);
    const bool pow2_table = (tsize & (tsize - 1)) == 0;
    const bool pow2_w = (W & (W - 1)) == 0;

    if (pow2_table && pow2_w)
        hashenc_kernel<true, true><<<grid, 256, 0, stream>>>(
            x0, y0, tables, seeds, tile_ptr, out, N, W, wshift, tsize, tsize - 1u);
    else if (pow2_table)
        hashenc_kernel<true, false><<<grid, 256, 0, stream>>>(
            x0, y0, tables, seeds, tile_ptr, out, N, W, wshift, tsize, tsize - 1u);
    else if (pow2_w)
        hashenc_kernel<false, true><<<grid, 256, 0, stream>>>(
            x0, y0, tables, seeds, tile_ptr, out, N, W, wshift, tsize, 0u);
    else
        hashenc_kernel<false, false><<<grid, 256, 0, stream>>>(
            x0, y0, tables, seeds, tile_ptr, out, N, W, wshift, tsize, 0u);
}